// Round 21
// baseline (512.422 us; speedup 1.0000x reference)
//
#include <hip/hip_runtime.h>
#include <hip/hip_cooperative_groups.h>
#include <math.h>

namespace cg = cooperative_groups;

#define HH 256
#define WW 256
#define NPIX (HH*WW)
#define GW (WW+4)
#define GH (HH+4)
#define NC (GW*GH)              // 67600
#define CHUNK 256
#define NCHUNKS ((NC + CHUNK - 1) / CHUNK)   // 265
#define EPSF 0.01f
// Verified gate (round 11): membership tightened by 3e-5 to match the
// reference realization's boundary decision. DO NOT CHANGE.
#define GATE 2.24997f

// 4-term contraction: sequential ascending, discrete mul+add, NO FMA.
__device__ __forceinline__ float dot4(const float* M, int i, float a0, float a1, float a2, float a3) {
    float s = __fmul_rn(M[i*4+0], a0);
    s = __fadd_rn(s, __fmul_rn(M[i*4+1], a1));
    s = __fadd_rn(s, __fmul_rn(M[i*4+2], a2));
    s = __fadd_rn(s, __fmul_rn(M[i*4+3], a3));
    return s;
}

// ONE cooperative kernel: zero -> proj+count+rgb -> chunk-scan -> offsets ->
// scatter -> gather. Phase bodies byte-identical to the round-20 champion;
// grid.sync() replaces the 5 inter-dispatch boundaries.
__global__ __launch_bounds__(256, 4) void mega_kernel(
    const float* __restrict__ pred, const float* __restrict__ alphas,
    const float* __restrict__ Kinv, const float* __restrict__ RT1,
    const float* __restrict__ RTi2, const float* __restrict__ Km,
    const float* __restrict__ src,
    float4* __restrict__ pts, int* __restrict__ counts, int* __restrict__ starts,
    int* __restrict__ cursor, int* __restrict__ bsum,
    float4* __restrict__ bpts, int* __restrict__ bids, float4* __restrict__ rgb,
    float* __restrict__ out, int bs)
{
    cg::grid_group grid = cg::this_grid();
    int tid = threadIdx.x;
    int T   = blockIdx.x * 256 + tid;
    int NT  = gridDim.x * 256;
    int npts = bs * NPIX;

    __shared__ float Ms[4][16];
    __shared__ int   sh[CHUNK];
    __shared__ float mz[128][8];
    __shared__ int   mi[128][8];
    __shared__ float ma[128][8];

    // ---- Phase A: zero counts ----
    int ncell = bs * NC;
    for (int i = T; i < ncell; i += NT) counts[i] = 0;
    grid.sync();

    // ---- Phase B: projection + per-cell count + rgb repack ----
    if (T < npts) {                      // whole block in/out (256 | NPIX)
        int b = T >> 16;
        int n = T & (NPIX - 1);
        if (tid < 64) {
            const float* srcs4[4] = {Kinv, RT1, RTi2, Km};
            Ms[tid >> 4][tid & 15] = srcs4[tid >> 4][b*16 + (tid & 15)];
        }
        __syncthreads();
        const float* KIs = Ms[0];
        const float* R1s = Ms[1];
        const float* R2s = Ms[2];
        const float* Ks  = Ms[3];

        float d = pred[T];
        float X = (float)(n & (WW-1));
        float Y = (float)(n >> 8);
        float p0 = __fmul_rn(X, d);
        float p1 = __fmul_rn(Y, d);
        float p2 = d;
        float p3 = 1.0f;
        float c0 = dot4(KIs, 0, p0, p1, p2, p3);
        float c1 = dot4(KIs, 1, p0, p1, p2, p3);
        float c2 = dot4(KIs, 2, p0, p1, p2, p3);
        float c3 = dot4(KIs, 3, p0, p1, p2, p3);
        float w0 = dot4(R1s, 0, c0, c1, c2, c3);
        float w1 = dot4(R1s, 1, c0, c1, c2, c3);
        float w2 = dot4(R1s, 2, c0, c1, c2, c3);
        float w3 = dot4(R1s, 3, c0, c1, c2, c3);
        float q0 = dot4(R2s, 0, w0, w1, w2, w3);
        float q1 = dot4(R2s, 1, w0, w1, w2, w3);
        float q2 = dot4(R2s, 2, w0, w1, w2, w3);
        float q3 = dot4(R2s, 3, w0, w1, w2, w3);
        float xy0 = dot4(Ks, 0, q0, q1, q2, q3);
        float xy1 = dot4(Ks, 1, q0, q1, q2, q3);
        float z   = dot4(Ks, 2, q0, q1, q2, q3);

        bool mask = fabsf(z) < EPSF;
        float zs = mask ? EPSF : z;
        float tx = __fdiv_rn(xy0, zs);
        tx = __fdiv_rn(tx, 255.0f);
        tx = __fmul_rn(tx, 2.0f);
        float sx = __fsub_rn(tx, 1.0f);
        float ty = __fdiv_rn(xy1, zs);
        ty = __fdiv_rn(ty, 255.0f);
        ty = __fmul_rn(ty, 2.0f);
        float sy = __fsub_rn(ty, 1.0f);
        float sxm = mask ? -10.0f : sx;
        float sym = mask ? -10.0f : sy;
        float zo  = mask ? -10.0f : z;
        float x = __fmul_rn(__fmul_rn(__fadd_rn(sxm, 1.0f), 0.5f), 255.0f);
        float y = __fmul_rn(__fmul_rn(__fadd_rn(sym, 1.0f), 0.5f), 255.0f);

        float al = alphas[T];
        pts[T] = make_float4(x, y, zo, al);

        float f0 = src[((size_t)b*3 + 0)*NPIX + n];
        float f1 = src[((size_t)b*3 + 1)*NPIX + n];
        float f2 = src[((size_t)b*3 + 2)*NPIX + n];
        rgb[T] = make_float4(f0, f1, f2, 0.f);

        if (zo > 0.0f) {
            float fx = floorf(x), fy = floorf(y);
            if (fx >= -2.0f && fx <= (float)(WW+1) && fy >= -2.0f && fy <= (float)(HH+1)) {
                int cx = (int)fx + 2, cy = (int)fy + 2;
                atomicAdd(&counts[(size_t)b*NC + cy*GW + cx], 1);
            }
        }
    }
    grid.sync();

    // ---- Phase C1: per-chunk local exclusive scan + chunk totals ----
    int ntot = bs * NCHUNKS;
    for (int c = blockIdx.x; c < ntot; c += gridDim.x) {
        int b = c / NCHUNKS;
        int chunk = c - b*NCHUNKS;
        int i = chunk*CHUNK + tid;
        int v = (i < NC) ? counts[(size_t)b*NC + i] : 0;
        sh[tid] = v;
        __syncthreads();
        for (int off = 1; off < CHUNK; off <<= 1) {
            int t2 = (tid >= off) ? sh[tid - off] : 0;
            __syncthreads();
            sh[tid] += t2;
            __syncthreads();
        }
        if (i < NC) starts[(size_t)b*(NC+1) + i] = sh[tid] - v;
        if (tid == CHUNK-1) bsum[b*NCHUNKS + chunk] = sh[tid];
        __syncthreads();
    }
    grid.sync();

    // ---- Phase C2: chunk offsets via masked reduction; emit starts+cursor ----
    for (int c = blockIdx.x; c < ntot; c += gridDim.x) {
        int b = c / NCHUNKS;
        int chunk = c - b*NCHUNKS;
        int v0 = (tid < chunk) ? bsum[b*NCHUNKS + tid] : 0;
        int i2 = tid + CHUNK;
        int v1 = (i2 < NCHUNKS && i2 < chunk) ? bsum[b*NCHUNKS + i2] : 0;
        sh[tid] = v0 + v1;
        __syncthreads();
        for (int off = CHUNK/2; off > 0; off >>= 1) {
            if (tid < off) sh[tid] += sh[tid + off];
            __syncthreads();
        }
        int offset = sh[0];
        int i = chunk*CHUNK + tid;
        if (i < NC) {
            int s = starts[(size_t)b*(NC+1) + i] + offset;
            starts[(size_t)b*(NC+1) + i] = s;
            cursor[(size_t)b*NC + i] = s;
        }
        if (chunk == NCHUNKS-1 && tid == 0)
            starts[(size_t)b*(NC+1) + NC] = offset + bsum[b*NCHUNKS + NCHUNKS-1];
        __syncthreads();
    }
    grid.sync();

    // ---- Phase D: counting-sort scatter ----
    if (T < npts) {
        int b = T >> 16;
        float4 r = pts[T];
        if (r.z > 0.0f) {
            float fx = floorf(r.x), fy = floorf(r.y);
            if (fx >= -2.0f && fx <= (float)(WW+1) && fy >= -2.0f && fy <= (float)(HH+1)) {
                int cx = (int)fx + 2, cy = (int)fy + 2;
                int pos = atomicAdd(&cursor[(size_t)b*NC + cy*GW + cx], 1);
                bpts[(size_t)b*NPIX + pos] = r;
                bids[(size_t)b*NPIX + pos] = T & (NPIX-1);
            }
        }
    }
    grid.sync();

    // ---- Phase E: gather, 4x4 provably-tight window, 2 workers/pixel ----
    {
        int lp = tid & 127;
        int w  = tid >> 7;
        int P  = blockIdx.x * 128 + lp;      // < bs*NPIX by grid construction
        int b  = P >> 16;
        int p  = P & (NPIX-1);
        int px = p & (WW-1);
        int py = p >> 8;
        const int* st = starts + (size_t)b*(NC+1);
        const int* ids = bids + (size_t)b*NPIX;
        const float4* B = bpts + (size_t)b*NPIX;

        int s0[4], e0[4];
#pragma unroll
        for (int r5 = 0; r5 < 4; ++r5) {
            int base = (py + r5)*GW + px;
            s0[r5] = st[base];
            e0[r5] = st[base + 4];
        }

        float zz[8]; int ii[8]; float aa[8];
#pragma unroll
        for (int k = 0; k < 8; ++k) { zz[k] = INFINITY; ii[k] = 0x7fffffff; aa[k] = 0.f; }

        float fpx = (float)px, fpy = (float)py;
#pragma unroll
        for (int r5 = 0; r5 < 4; ++r5) {
            int s = s0[r5], e = e0[r5];
            int cnt = e - s;
            int half = (cnt + 1) >> 1;
            int js = w ? (s + half) : s;
            int je = w ? e : (s + half);
            for (int j = js; j < je; ++j) {
                float4 r = B[j];
                float dx = __fsub_rn(fpx, r.x);
                float dy = __fsub_rn(fpy, r.y);
                float d2 = __fadd_rn(__fmul_rn(dx, dx), __fmul_rn(dy, dy));
                if (!(d2 <= GATE)) continue;
                int n = ids[j];
                float dn = __fdiv_rn(d2, 2.25f);
                dn = fminf(fmaxf(dn, 0.001f), 1.0f);
                float ta = __fmul_rn(__fsub_rn(1.0f, sqrtf(dn)), r.w);
                float tz = r.z; int tn = n;
#pragma unroll
                for (int k = 0; k < 8; ++k) {
                    bool lt = (tz < zz[k]) || (tz == zz[k] && tn < ii[k]);
                    float oz = zz[k]; int oi = ii[k]; float oa = aa[k];
                    zz[k] = lt ? tz : oz;  ii[k] = lt ? tn : oi;  aa[k] = lt ? ta : oa;
                    tz = lt ? oz : tz;     tn = lt ? oi : tn;     ta = lt ? oa : ta;
                }
            }
        }

        if (w == 1) {
#pragma unroll
            for (int k = 0; k < 8; ++k) { mz[lp][k] = zz[k]; mi[lp][k] = ii[k]; ma[lp][k] = aa[k]; }
        }
        __syncthreads();
        if (w == 0) {
            const float4* F = rgb + (size_t)b*NPIX;
            float T2 = 1.0f, c0 = 0.f, c1 = 0.f, c2 = 0.f;
            int ia = 0, ib = 0;
#pragma unroll
            for (int k = 0; k < 8; ++k) {
                float za = zz[ia]; int na = ii[ia];
                float zb = mz[lp][ib]; int nb = mi[lp][ib];
                bool ta = (za < zb) || (za == zb && na < nb);
                int nm = ta ? na : nb;
                float am = ta ? aa[ia] : ma[lp][ib];
                ia += ta ? 1 : 0;
                ib += ta ? 0 : 1;
                if (nm != 0x7fffffff) {
                    float wgt = __fmul_rn(am, T2);
                    float4 f = F[nm];
                    c0 = __fadd_rn(c0, __fmul_rn(wgt, f.x));
                    c1 = __fadd_rn(c1, __fmul_rn(wgt, f.y));
                    c2 = __fadd_rn(c2, __fmul_rn(wgt, f.z));
                    T2 = __fmul_rn(T2, __fsub_rn(1.0f, am));
                }
            }
            out[((size_t)b*3 + 0)*NPIX + p] = c0;
            out[((size_t)b*3 + 1)*NPIX + p] = c1;
            out[((size_t)b*3 + 2)*NPIX + p] = c2;
        }
    }
}

extern "C" void kernel_launch(void* const* d_in, const int* in_sizes, int n_in,
                              void* d_out, int out_size, void* d_ws, size_t ws_size,
                              hipStream_t stream) {
    const float* alphas = (const float*)d_in[0];
    const float* src    = (const float*)d_in[1];
    const float* pred   = (const float*)d_in[2];
    const float* Kmat   = (const float*)d_in[3];
    const float* Kinv   = (const float*)d_in[4];
    const float* RT1    = (const float*)d_in[5];
    const float* RTinv2 = (const float*)d_in[8];
    float* out = (float*)d_out;

    int bs = in_sizes[0] / NPIX;

    char* w = (char*)d_ws;
    size_t need = 0;
    float4* pts   = (float4*)(w);                 need += (size_t)bs*NPIX*sizeof(float4);
    float4* bpts  = (float4*)(w + need);          need += (size_t)bs*NPIX*sizeof(float4);
    float4* rgb   = (float4*)(w + need);          need += (size_t)bs*NPIX*sizeof(float4);
    int*    cnts  = (int*)(w + need);             need += (size_t)bs*NC*sizeof(int);
    int*    strts = (int*)(w + need);             need += (size_t)bs*(NC+1)*sizeof(int);
    int*    curs  = (int*)(w + need);             need += (size_t)bs*NC*sizeof(int);
    int*    bids  = (int*)(w + need);             need += (size_t)bs*NPIX*sizeof(int);
    int*    bsum  = (int*)(w + need);             need += (size_t)bs*NCHUNKS*sizeof(int);
    if (ws_size < need) return;

    void* args[] = {
        (void*)&pred, (void*)&alphas, (void*)&Kinv, (void*)&RT1, (void*)&RTinv2,
        (void*)&Kmat, (void*)&src,
        (void*)&pts, (void*)&cnts, (void*)&strts, (void*)&curs, (void*)&bsum,
        (void*)&bpts, (void*)&bids, (void*)&rgb, (void*)&out, (void*)&bs
    };
    hipLaunchCooperativeKernel((void*)mega_kernel, dim3(bs*512), dim3(256),
                               args, 0, stream);
}

// Round 22
// 53.541 us; speedup vs baseline: 9.5707x; 9.5707x over previous
//
#include <hip/hip_runtime.h>
#include <math.h>

#define HH 256
#define WW 256
#define NPIX (HH*WW)
#define GW (WW+4)
#define GH (HH+4)
#define NC (GW*GH)              // 67600
#define CHUNK 256
#define NCHUNKS ((NC + CHUNK - 1) / CHUNK)   // 265
#define EPSF 0.01f
// Verified gate (round 11): membership tightened by 3e-5 to match the
// reference realization's boundary decision. DO NOT CHANGE.
#define GATE 2.24997f

// 4-term contraction: sequential ascending, discrete mul+add, NO FMA.
__device__ __forceinline__ float dot4(const float* M, int i, float a0, float a1, float a2, float a3) {
    float s = __fmul_rn(M[i*4+0], a0);
    s = __fadd_rn(s, __fmul_rn(M[i*4+1], a1));
    s = __fadd_rn(s, __fmul_rn(M[i*4+2], a2));
    s = __fadd_rn(s, __fmul_rn(M[i*4+3], a3));
    return s;
}

__global__ void zero_kernel(int4* __restrict__ p, int n4) {
    int i = blockIdx.x * blockDim.x + threadIdx.x;
    if (i < n4) p[i] = make_int4(0, 0, 0, 0);
}

// Strict-f32 projection (byte-identical math to the passing kernels),
// plus per-cell count for the counting sort.
__global__ void proj_kernel(const float* __restrict__ pred, const float* __restrict__ alphas,
                            const float* __restrict__ Kinv, const float* __restrict__ RT1,
                            const float* __restrict__ RTi2, const float* __restrict__ Km,
                            float4* __restrict__ pts, int* __restrict__ counts) {
    int b = blockIdx.y;
    int n = blockIdx.x * blockDim.x + threadIdx.x;
    __shared__ float Ms[4][16];
    int t = threadIdx.x;
    if (t < 64) {
        const float* srcs[4] = {Kinv, RT1, RTi2, Km};
        Ms[t >> 4][t & 15] = srcs[t >> 4][b*16 + (t & 15)];
    }
    __syncthreads();
    const float* KIs = Ms[0];
    const float* R1s = Ms[1];
    const float* R2s = Ms[2];
    const float* Ks  = Ms[3];

    float d = pred[b*NPIX + n];
    float X = (float)(n & (WW-1));
    float Y = (float)(n >> 8);
    float p0 = __fmul_rn(X, d);
    float p1 = __fmul_rn(Y, d);
    float p2 = d;
    float p3 = 1.0f;
    float c0 = dot4(KIs, 0, p0, p1, p2, p3);
    float c1 = dot4(KIs, 1, p0, p1, p2, p3);
    float c2 = dot4(KIs, 2, p0, p1, p2, p3);
    float c3 = dot4(KIs, 3, p0, p1, p2, p3);
    float w0 = dot4(R1s, 0, c0, c1, c2, c3);
    float w1 = dot4(R1s, 1, c0, c1, c2, c3);
    float w2 = dot4(R1s, 2, c0, c1, c2, c3);
    float w3 = dot4(R1s, 3, c0, c1, c2, c3);
    float q0 = dot4(R2s, 0, w0, w1, w2, w3);
    float q1 = dot4(R2s, 1, w0, w1, w2, w3);
    float q2 = dot4(R2s, 2, w0, w1, w2, w3);
    float q3 = dot4(R2s, 3, w0, w1, w2, w3);
    float xy0 = dot4(Ks, 0, q0, q1, q2, q3);
    float xy1 = dot4(Ks, 1, q0, q1, q2, q3);
    float z   = dot4(Ks, 2, q0, q1, q2, q3);

    bool mask = fabsf(z) < EPSF;
    float zs = mask ? EPSF : z;
    float tx = __fdiv_rn(xy0, zs);
    tx = __fdiv_rn(tx, 255.0f);
    tx = __fmul_rn(tx, 2.0f);
    float sx = __fsub_rn(tx, 1.0f);
    float ty = __fdiv_rn(xy1, zs);
    ty = __fdiv_rn(ty, 255.0f);
    ty = __fmul_rn(ty, 2.0f);
    float sy = __fsub_rn(ty, 1.0f);
    float sxm = mask ? -10.0f : sx;
    float sym = mask ? -10.0f : sy;
    float zo  = mask ? -10.0f : z;
    float x = __fmul_rn(__fmul_rn(__fadd_rn(sxm, 1.0f), 0.5f), 255.0f);
    float y = __fmul_rn(__fmul_rn(__fadd_rn(sym, 1.0f), 0.5f), 255.0f);

    float al = alphas[b*NPIX + n];
    pts[(size_t)b*NPIX + n] = make_float4(x, y, zo, al);

    if (zo > 0.0f) {
        float fx = floorf(x), fy = floorf(y);
        if (fx >= -2.0f && fx <= (float)(WW+1) && fy >= -2.0f && fy <= (float)(HH+1)) {
            int cx = (int)fx + 2, cy = (int)fy + 2;
            atomicAdd(&counts[(size_t)b*NC + cy*GW + cx], 1);
        }
    }
}

// Phase 1: per-chunk local exclusive scan + chunk totals.
__global__ void scan_part(const int* __restrict__ counts, int* __restrict__ starts,
                          int* __restrict__ bsum) {
    int b = blockIdx.y;
    int chunk = blockIdx.x;
    int tid = threadIdx.x;
    int i = chunk*CHUNK + tid;
    int v = (i < NC) ? counts[(size_t)b*NC + i] : 0;
    __shared__ int sh[CHUNK];
    sh[tid] = v;
    __syncthreads();
    for (int off = 1; off < CHUNK; off <<= 1) {
        int t = (tid >= off) ? sh[tid - off] : 0;
        __syncthreads();
        sh[tid] += t;
        __syncthreads();
    }
    if (i < NC) starts[(size_t)b*(NC+1) + i] = sh[tid] - v;
    if (tid == CHUNK-1) bsum[b*NCHUNKS + chunk] = sh[tid];
}

// Phase 2+3 fused: per-block masked reduction of chunk totals -> offset.
__global__ void scan_add(int* __restrict__ starts, const int* __restrict__ bsum,
                         int* __restrict__ cursor) {
    int b = blockIdx.y;
    int chunk = blockIdx.x;
    int tid = threadIdx.x;
    __shared__ int sh[CHUNK];
    int v0 = (tid < chunk) ? bsum[b*NCHUNKS + tid] : 0;
    int i2 = tid + CHUNK;
    int v1 = (i2 < NCHUNKS && i2 < chunk) ? bsum[b*NCHUNKS + i2] : 0;
    sh[tid] = v0 + v1;
    __syncthreads();
    for (int off = CHUNK/2; off > 0; off >>= 1) {
        if (tid < off) sh[tid] += sh[tid + off];
        __syncthreads();
    }
    int offset = sh[0];
    int i = chunk*CHUNK + tid;
    if (i < NC) {
        int s = starts[(size_t)b*(NC+1) + i] + offset;
        starts[(size_t)b*(NC+1) + i] = s;
        cursor[(size_t)b*NC + i] = s;
    }
    if (chunk == NCHUNKS-1 && tid == 0)
        starts[(size_t)b*(NC+1) + NC] = offset + bsum[b*NCHUNKS + NCHUNKS-1];
}

// Counting-sort scatter: full point record + id into cell-ordered arrays,
// plus rgb repack for the gather epilogue.
__global__ void scatter_kernel(const float4* __restrict__ pts, int* __restrict__ cursor,
                               float4* __restrict__ bpts, int* __restrict__ bids,
                               const float* __restrict__ src, float4* __restrict__ rgb) {
    int b = blockIdx.y;
    int n = blockIdx.x * blockDim.x + threadIdx.x;
    float4 r = pts[(size_t)b*NPIX + n];
    float f0 = src[((size_t)b*3 + 0)*NPIX + n];
    float f1 = src[((size_t)b*3 + 1)*NPIX + n];
    float f2 = src[((size_t)b*3 + 2)*NPIX + n];
    rgb[(size_t)b*NPIX + n] = make_float4(f0, f1, f2, 0.f);
    if (r.z > 0.0f) {
        float fx = floorf(r.x), fy = floorf(r.y);
        if (fx >= -2.0f && fx <= (float)(WW+1) && fy >= -2.0f && fy <= (float)(HH+1)) {
            int cx = (int)fx + 2, cy = (int)fy + 2;
            int pos = atomicAdd(&cursor[(size_t)b*NC + cy*GW + cx], 1);
            bpts[(size_t)b*NPIX + pos] = r;
            bids[(size_t)b*NPIX + pos] = n;
        }
    }
}

// Gather v6: PROVABLY-TIGHT 4x4 cell window. floor(x)=px+2 => dx>=2 => d2>=4
// > GATE (exact in f32, monotone ops) — same for rows — so the +2 cell column/
// row of the reference's 5x5 window can never contribute: scan only
// floors in [p-2, p+1] (padded cells [p, p+3]). 2 workers per pixel split each
// row-range in half; LDS publish + 2-way merge by (z,id); worker 0 composites.
// Decision set and all f32 ops byte-identical to the passing kernels.
__global__ void gather_kernel(const float4* __restrict__ bpts, const int* __restrict__ starts,
                              const int* __restrict__ bids, const float4* __restrict__ rgb,
                              float* __restrict__ out) {
    int b  = blockIdx.y;
    int lp = threadIdx.x & 127;          // local pixel 0..127
    int w  = threadIdx.x >> 7;           // worker 0/1
    int p  = blockIdx.x * 128 + lp;
    int px = p & (WW-1);
    int py = p >> 8;
    const int* st = starts + (size_t)b*(NC+1);
    const int* ids = bids + (size_t)b*NPIX;
    const float4* B = bpts + (size_t)b*NPIX;

    // Prefetch the 4 row-range pairs (independent loads).
    int s0[4], e0[4];
#pragma unroll
    for (int r5 = 0; r5 < 4; ++r5) {
        int base = (py + r5)*GW + px;
        s0[r5] = st[base];
        e0[r5] = st[base + 4];   // 4 consecutive cells = one contiguous range
    }

    float zz[8]; int ii[8]; float aa[8];
#pragma unroll
    for (int k = 0; k < 8; ++k) { zz[k] = INFINITY; ii[k] = 0x7fffffff; aa[k] = 0.f; }

    float fpx = (float)px, fpy = (float)py;
#pragma unroll
    for (int r5 = 0; r5 < 4; ++r5) {
        int s = s0[r5], e = e0[r5];
        int cnt = e - s;
        int half = (cnt + 1) >> 1;
        int js = w ? (s + half) : s;
        int je = w ? e : (s + half);
        for (int j = js; j < je; ++j) {
            float4 r = B[j];
            float dx = __fsub_rn(fpx, r.x);
            float dy = __fsub_rn(fpy, r.y);
            float d2 = __fadd_rn(__fmul_rn(dx, dx), __fmul_rn(dy, dy));
            if (!(d2 <= GATE)) continue;
            int n = ids[j];
            float dn = __fdiv_rn(d2, 2.25f);
            dn = fminf(fmaxf(dn, 0.001f), 1.0f);
            float ta = __fmul_rn(__fsub_rn(1.0f, sqrtf(dn)), r.w);
            float tz = r.z; int tn = n;
#pragma unroll
            for (int k = 0; k < 8; ++k) {
                bool lt = (tz < zz[k]) || (tz == zz[k] && tn < ii[k]);
                float oz = zz[k]; int oi = ii[k]; float oa = aa[k];
                zz[k] = lt ? tz : oz;  ii[k] = lt ? tn : oi;  aa[k] = lt ? ta : oa;
                tz = lt ? oz : tz;     tn = lt ? oi : tn;     ta = lt ? oa : ta;
            }
        }
    }

    // Publish worker 1's top-8; worker 0 merges.
    __shared__ float mz[128][8];
    __shared__ int   mi[128][8];
    __shared__ float ma[128][8];
    if (w == 1) {
#pragma unroll
        for (int k = 0; k < 8; ++k) { mz[lp][k] = zz[k]; mi[lp][k] = ii[k]; ma[lp][k] = aa[k]; }
    }
    __syncthreads();
    if (w == 0) {
        const float4* F = rgb + (size_t)b*NPIX;
        float T = 1.0f, c0 = 0.f, c1 = 0.f, c2 = 0.f;
        int ia = 0, ib = 0;
#pragma unroll
        for (int k = 0; k < 8; ++k) {
            float za = zz[ia]; int na = ii[ia];
            float zb = mz[lp][ib]; int nb = mi[lp][ib];
            bool ta = (za < zb) || (za == zb && na < nb);
            int nm = ta ? na : nb;
            float am = ta ? aa[ia] : ma[lp][ib];
            ia += ta ? 1 : 0;
            ib += ta ? 0 : 1;
            if (nm != 0x7fffffff) {
                float wgt = __fmul_rn(am, T);
                float4 f = F[nm];
                c0 = __fadd_rn(c0, __fmul_rn(wgt, f.x));
                c1 = __fadd_rn(c1, __fmul_rn(wgt, f.y));
                c2 = __fadd_rn(c2, __fmul_rn(wgt, f.z));
                T = __fmul_rn(T, __fsub_rn(1.0f, am));
            }
        }
        out[((size_t)b*3 + 0)*NPIX + p] = c0;
        out[((size_t)b*3 + 1)*NPIX + p] = c1;
        out[((size_t)b*3 + 2)*NPIX + p] = c2;
    }
}

extern "C" void kernel_launch(void* const* d_in, const int* in_sizes, int n_in,
                              void* d_out, int out_size, void* d_ws, size_t ws_size,
                              hipStream_t stream) {
    const float* alphas = (const float*)d_in[0];
    const float* src    = (const float*)d_in[1];
    const float* pred   = (const float*)d_in[2];
    const float* Kmat   = (const float*)d_in[3];
    const float* Kinv   = (const float*)d_in[4];
    const float* RT1    = (const float*)d_in[5];
    const float* RTinv2 = (const float*)d_in[8];
    float* out = (float*)d_out;

    int bs = in_sizes[0] / NPIX;

    char* w = (char*)d_ws;
    size_t need = 0;
    float4* pts   = (float4*)(w);                 need += (size_t)bs*NPIX*sizeof(float4);
    float4* bpts  = (float4*)(w + need);          need += (size_t)bs*NPIX*sizeof(float4);
    float4* rgb   = (float4*)(w + need);          need += (size_t)bs*NPIX*sizeof(float4);
    int*    cnts  = (int*)(w + need);             need += (size_t)bs*NC*sizeof(int);
    int*    strts = (int*)(w + need);             need += (size_t)bs*(NC+1)*sizeof(int);
    int*    curs  = (int*)(w + need);             need += (size_t)bs*NC*sizeof(int);
    int*    bids  = (int*)(w + need);             need += (size_t)bs*NPIX*sizeof(int);
    int*    bsum  = (int*)(w + need);             need += (size_t)bs*NCHUNKS*sizeof(int);
    if (ws_size < need) return;

    int n4 = bs*NC/4;
    zero_kernel<<<(n4 + 255)/256, 256, 0, stream>>>((int4*)cnts, n4);
    proj_kernel<<<dim3(NPIX/256, bs), 256, 0, stream>>>(pred, alphas, Kinv, RT1, RTinv2, Kmat, pts, cnts);
    scan_part<<<dim3(NCHUNKS, bs), CHUNK, 0, stream>>>(cnts, strts, bsum);
    scan_add<<<dim3(NCHUNKS, bs), CHUNK, 0, stream>>>(strts, bsum, curs);
    scatter_kernel<<<dim3(NPIX/256, bs), 256, 0, stream>>>(pts, curs, bpts, bids, src, rgb);
    gather_kernel<<<dim3(NPIX/128, bs), 256, 0, stream>>>(bpts, strts, bids, rgb, out);
}